// Round 10
// baseline (180.074 us; speedup 1.0000x reference)
//
#include <hip/hip_runtime.h>
#include <hip/hip_bf16.h>
#include <stdint.h>

#define HID 2048
#define NH  32
#define HD  64
#define NB  8
#define NS  16
#define PAST 4096

// log2(e) / sqrt(D) = 1.4426950408889634 / 8
#define QSCALE 0.18033688011112042591f

typedef __attribute__((ext_vector_type(8))) short short8;
typedef __attribute__((ext_vector_type(4))) short short4v;
typedef __attribute__((ext_vector_type(4))) float f32x4;

#define MFMA(a, b, c) __builtin_amdgcn_mfma_f32_16x16x32_bf16((a), (b), (c), 0, 0, 0)

#define PART_STRIDE 1088  // 16 m + 16 l + 16*64 O + pad, floats
#define NSPLIT 4          // attn splits per (b,h); 1024 pos per split
#define MATSZ (128 * HID) // elements of one projection output
#define VPAD 68           // padded row stride (f32) of per-wave V slab

static __device__ __forceinline__ short f2bf(float f) {
    __hip_bfloat16 h = __float2bfloat16(f);
    return *reinterpret_cast<short*>(&h);
}

static __device__ __forceinline__ short8 pack8(float4 a, float4 b) {
    short8 r;
    r[0] = f2bf(a.x); r[1] = f2bf(a.y); r[2] = f2bf(a.z); r[3] = f2bf(a.w);
    r[4] = f2bf(b.x); r[5] = f2bf(b.y); r[6] = f2bf(b.z); r[7] = f2bf(b.w);
    return r;
}

static __device__ __forceinline__ short8 pack8s(float4 a, float4 b, float s) {
    short8 r;
    r[0] = f2bf(a.x * s); r[1] = f2bf(a.y * s); r[2] = f2bf(a.z * s); r[3] = f2bf(a.w * s);
    r[4] = f2bf(b.x * s); r[5] = f2bf(b.y * s); r[6] = f2bf(b.z * s); r[7] = f2bf(b.w * s);
    return r;
}

// ---------------- hidden fp32 -> bf16 ----------------
__global__ __launch_bounds__(256) void cvt_kernel(const float* __restrict__ in,
                                                  short* __restrict__ out) {
    int i = (blockIdx.x * 256 + threadIdx.x) * 4;
    float4 v = *reinterpret_cast<const float4*>(in + i);
    short4v o;
    o[0] = f2bf(v.x); o[1] = f2bf(v.y); o[2] = f2bf(v.z); o[3] = f2bf(v.w);
    *reinterpret_cast<short4v*>(out + i) = o;
}

// ------- Ypart[mat*4+ks] = Xbf16 @ W^T slice (M=128, K-split x4, N=16) -----
__global__ __launch_bounds__(128) void proj_kernel(
        const short* __restrict__ X,
        const float* __restrict__ W0, const float* __restrict__ W1,
        const float* __restrict__ W2,
        float* __restrict__ Yp) {
    int mat   = blockIdx.x >> 9;
    int rest  = blockIdx.x & 511;
    int strip = rest >> 2, ks = rest & 3;
    int nbase = strip * 16;
    int k0    = ks * 512;
    const float* W = (mat == 0) ? W0 : (mat == 1) ? W1 : W2;
    float* Y = Yp + (size_t)(mat * 4 + ks) * MATSZ;

    int lane = threadIdx.x & 63;
    int wave = threadIdx.x >> 6;
    int lr = lane & 15, g = lane >> 4;

    f32x4 acc0 = {0.f, 0.f, 0.f, 0.f};
    f32x4 acc1 = {0.f, 0.f, 0.f, 0.f};
    f32x4 acc2 = {0.f, 0.f, 0.f, 0.f};
    f32x4 acc3 = {0.f, 0.f, 0.f, 0.f};

    const short* xr = X + (size_t)(wave * 64 + lr) * HID + g * 8 + k0;
    const float* wr = W + (size_t)(nbase + lr) * HID + g * 8 + k0;

    #pragma unroll 4
    for (int kc = 0; kc < 512; kc += 32) {
        float4 w0 = *reinterpret_cast<const float4*>(wr + kc);
        float4 w1 = *reinterpret_cast<const float4*>(wr + kc + 4);
        short8 bb = pack8(w0, w1);
        short8 a0 = *reinterpret_cast<const short8*>(xr + kc);
        short8 a1 = *reinterpret_cast<const short8*>(xr + (size_t)16 * HID + kc);
        short8 a2 = *reinterpret_cast<const short8*>(xr + (size_t)32 * HID + kc);
        short8 a3 = *reinterpret_cast<const short8*>(xr + (size_t)48 * HID + kc);
        acc0 = MFMA(a0, bb, acc0);
        acc1 = MFMA(a1, bb, acc1);
        acc2 = MFMA(a2, bb, acc2);
        acc3 = MFMA(a3, bb, acc3);
    }
    #define STACC(accv, f) do { \
        Y[(size_t)(wave * 64 + (f) * 16 + (g << 2) + 0) * HID + nbase + lr] = accv[0]; \
        Y[(size_t)(wave * 64 + (f) * 16 + (g << 2) + 1) * HID + nbase + lr] = accv[1]; \
        Y[(size_t)(wave * 64 + (f) * 16 + (g << 2) + 2) * HID + nbase + lr] = accv[2]; \
        Y[(size_t)(wave * 64 + (f) * 16 + (g << 2) + 3) * HID + nbase + lr] = accv[3]; \
    } while (0)
    STACC(acc0, 0); STACC(acc1, 1); STACC(acc2, 2); STACC(acc3, 3);
    #undef STACC
}

// -------- sum the 4 K-slice partials ------------------------------------
__global__ __launch_bounds__(256) void merge4_kernel(
        const float* __restrict__ Yp,
        float* __restrict__ Y0, float* __restrict__ Y1, float* __restrict__ Y2) {
    int mat = blockIdx.x >> 8;
    int blk = blockIdx.x & 255;
    float* Y = (mat == 0) ? Y0 : (mat == 1) ? Y1 : Y2;
    const float* P = Yp + (size_t)mat * 4 * MATSZ;
    int idx = blk * 1024 + threadIdx.x * 4;
    float4 a = *reinterpret_cast<const float4*>(P + idx);
    float4 b = *reinterpret_cast<const float4*>(P + MATSZ + idx);
    float4 c = *reinterpret_cast<const float4*>(P + 2 * MATSZ + idx);
    float4 d = *reinterpret_cast<const float4*>(P + 3 * MATSZ + idx);
    float4 s;
    s.x = a.x + b.x + c.x + d.x;
    s.y = a.y + b.y + c.y + d.y;
    s.z = a.z + b.z + c.z + d.z;
    s.w = a.w + b.w + c.w + d.w;
    *reinterpret_cast<float4*>(Y + idx) = s;
}

// ---------------- fused attention, 4 blocks per (b,h) -------------------
// blockIdx.x = bh*4 + split. 256 threads = 4 waves. Per 64-pos tile, wave w
// owns positions [w*16, w*16+16). V path is a REG round-trip (no
// global_load_lds => no conservative vmcnt(0) before ds_read): 4 coalesced
// float4 loads issued one tile ahead, ds_write_b128 into a padded [16][68]
// f32 slab placed AFTER the current tile's PV (T14 issue-early/write-late).
// K is register-double-buffered one tile ahead.
__global__ __launch_bounds__(256, 4) void attn_kernel(
        const float* __restrict__ q,
        const float* __restrict__ knew, const float* __restrict__ vnew,
        const float* __restrict__ pastK, const float* __restrict__ pastV,
        float* __restrict__ parts) {
    __shared__ __align__(16) float lds_v[4][2][16 * VPAD];   // ~34.8 KB
    __shared__ float s_m[4][16];
    __shared__ float s_l[4][16];

    int bid = blockIdx.x;
    int bh = bid >> 2, split = bid & 3;
    int b = bh >> 5, h = bh & 31;
    int wave = threadIdx.x >> 6, lane = threadIdx.x & 63;
    int lq = lane & 15, g = lane >> 4;
    int vrow = lane >> 4;        // row-within-4 for V loads/stores
    int vcol = (lane & 15) * 4;  // d-offset for V loads/stores

    // Q fragments (B operand of swapped QK^T), pre-scaled by log2(e)/8
    const float* qp = q + (size_t)(b * NS + lq) * HID + h * HD + g * 8;
    short8 qf0, qf1;
    {
        float4 a0 = *reinterpret_cast<const float4*>(qp);
        float4 a1 = *reinterpret_cast<const float4*>(qp + 4);
        float4 a2 = *reinterpret_cast<const float4*>(qp + 32);
        float4 a3 = *reinterpret_cast<const float4*>(qp + 36);
        qf0 = pack8s(a0, a1, QSCALE);
        qf1 = pack8s(a2, a3, QSCALE);
    }

    f32x4 o0 = {0.f, 0.f, 0.f, 0.f};
    f32x4 o1 = {0.f, 0.f, 0.f, 0.f};
    f32x4 o2 = {0.f, 0.f, 0.f, 0.f};
    f32x4 o3 = {0.f, 0.f, 0.f, 0.f};
    float m = -__builtin_inff(), lsum = 0.0f;

    const float* ksplit = pastK + (size_t)bh * PAST * HD + (size_t)split * 1024 * HD;
    const float* vsplit = pastV + (size_t)bh * PAST * HD + (size_t)split * 1024 * HD;

    // K rows for tile T -> 4 named float4
    #define ISSUE_K(T, A, Bv, C, D) do { \
        const float* kr_ = ksplit + (size_t)((T) * 64 + wave * 16 + lq) * HD + (g << 3); \
        A  = *reinterpret_cast<const float4*>(kr_); \
        Bv = *reinterpret_cast<const float4*>(kr_ + 4); \
        C  = *reinterpret_cast<const float4*>(kr_ + 32); \
        D  = *reinterpret_cast<const float4*>(kr_ + 36); \
    } while (0)

    // V rows [wave*16, +16) of tile T -> 4 named float4 (coalesced 256B/16 lanes)
    #define ISSUE_V(T, V0, V1, V2, V3) do { \
        const float* vr_ = vsplit + (size_t)((T) * 64 + wave * 16) * HD; \
        V0 = *reinterpret_cast<const float4*>(vr_ + (0 * 4 + vrow) * HD + vcol); \
        V1 = *reinterpret_cast<const float4*>(vr_ + (1 * 4 + vrow) * HD + vcol); \
        V2 = *reinterpret_cast<const float4*>(vr_ + (2 * 4 + vrow) * HD + vcol); \
        V3 = *reinterpret_cast<const float4*>(vr_ + (3 * 4 + vrow) * HD + vcol); \
    } while (0)

    // write staged V regs into slab BUF (linear [16][VPAD], b128 stores)
    #define DSW(V0, V1, V2, V3, BUF) do { \
        float* ds_ = &lds_v[wave][BUF][0]; \
        *reinterpret_cast<float4*>(ds_ + (0 * 4 + vrow) * VPAD + vcol) = V0; \
        *reinterpret_cast<float4*>(ds_ + (1 * 4 + vrow) * VPAD + vcol) = V1; \
        *reinterpret_cast<float4*>(ds_ + (2 * 4 + vrow) * VPAD + vcol) = V2; \
        *reinterpret_cast<float4*>(ds_ + (3 * 4 + vrow) * VPAD + vcol) = V3; \
    } while (0)

    // QK^T + online softmax for one tile; emits bf16 P fragment
    #define QKSM(A, Bv, C, D, PF) do { \
        short8 af0 = pack8(A, Bv); \
        short8 af1 = pack8(C, D); \
        f32x4 sv = {0.f, 0.f, 0.f, 0.f}; \
        sv = MFMA(af0, qf0, sv); \
        sv = MFMA(af1, qf1, sv); \
        float tmax = fmaxf(fmaxf(sv[0], sv[1]), fmaxf(sv[2], sv[3])); \
        tmax = fmaxf(tmax, __shfl_xor(tmax, 16)); \
        tmax = fmaxf(tmax, __shfl_xor(tmax, 32)); \
        float mn = fmaxf(m, tmax); \
        float alpha = exp2f(m - mn); \
        float e0 = exp2f(sv[0] - mn); \
        float e1 = exp2f(sv[1] - mn); \
        float e2 = exp2f(sv[2] - mn); \
        float e3 = exp2f(sv[3] - mn); \
        float rsum = e0 + e1 + e2 + e3; \
        rsum += __shfl_xor(rsum, 16); \
        rsum += __shfl_xor(rsum, 32); \
        lsum = lsum * alpha + rsum; \
        m = mn; \
        o0 *= alpha; o1 *= alpha; o2 *= alpha; o3 *= alpha; \
        PF[0] = f2bf(e0); PF[1] = f2bf(e1); PF[2] = f2bf(e2); PF[3] = f2bf(e3); \
        PF[4] = 0; PF[5] = 0; PF[6] = 0; PF[7] = 0; \
    } while (0)

    // PV from slab BUF: vf[j] = V[pos=g*4+j][dcol], banks 2-way (free)
    #define PV(BUF, PF) do { \
        const float* vc = &lds_v[wave][BUF][(g << 2) * VPAD]; \
        short8 vf; \
        vf[4] = 0; vf[5] = 0; vf[6] = 0; vf[7] = 0; \
        vf[0] = f2bf(vc[0 * VPAD + lq]);      vf[1] = f2bf(vc[1 * VPAD + lq]); \
        vf[2] = f2bf(vc[2 * VPAD + lq]);      vf[3] = f2bf(vc[3 * VPAD + lq]); \
        o0 = MFMA(vf, PF, o0); \
        vf[0] = f2bf(vc[0 * VPAD + 16 + lq]); vf[1] = f2bf(vc[1 * VPAD + 16 + lq]); \
        vf[2] = f2bf(vc[2 * VPAD + 16 + lq]); vf[3] = f2bf(vc[3 * VPAD + 16 + lq]); \
        o1 = MFMA(vf, PF, o1); \
        vf[0] = f2bf(vc[0 * VPAD + 32 + lq]); vf[1] = f2bf(vc[1 * VPAD + 32 + lq]); \
        vf[2] = f2bf(vc[2 * VPAD + 32 + lq]); vf[3] = f2bf(vc[3 * VPAD + 32 + lq]); \
        o2 = MFMA(vf, PF, o2); \
        vf[0] = f2bf(vc[0 * VPAD + 48 + lq]); vf[1] = f2bf(vc[1 * VPAD + 48 + lq]); \
        vf[2] = f2bf(vc[2 * VPAD + 48 + lq]); vf[3] = f2bf(vc[3 * VPAD + 48 + lq]); \
        o3 = MFMA(vf, PF, o3); \
    } while (0)

    float4 kA0, kA1, kA2, kA3, kB0, kB1, kB2, kB3;
    float4 vA0, vA1, vA2, vA3, vB0, vB1, vB2, vB3;

    // prologue: tile 0 -> regs, V into buf0
    ISSUE_V(0, vA0, vA1, vA2, vA3);
    ISSUE_K(0, kA0, kA1, kA2, kA3);
    DSW(vA0, vA1, vA2, vA3, 0);

    #pragma unroll 1
    for (int tt = 0; tt < 8; ++tt) {
        // prefetch odd tile 2tt+1
        ISSUE_V(2 * tt + 1, vB0, vB1, vB2, vB3);
        ISSUE_K(2 * tt + 1, kB0, kB1, kB2, kB3);
        // compute even tile 2tt from kA/buf0
        short8 pfE;
        QKSM(kA0, kA1, kA2, kA3, pfE);
        PV(0, pfE);
        DSW(vB0, vB1, vB2, vB3, 1);   // waits (counted) for vB only
        // prefetch even tile 2tt+2
        if (tt < 7) {
            ISSUE_V(2 * tt + 2, vA0, vA1, vA2, vA3);
            ISSUE_K(2 * tt + 2, kA0, kA1, kA2, kA3);
        }
        // compute odd tile 2tt+1 from kB/buf1
        short8 pfO;
        QKSM(kB0, kB1, kB2, kB3, pfO);
        PV(1, pfO);
        if (tt < 7) DSW(vA0, vA1, vA2, vA3, 0);
    }
    #undef PV
    #undef QKSM
    #undef DSW
    #undef ISSUE_V
    #undef ISSUE_K

    // ---- the 16 new tokens (wave 0 of split-0 block) ----
    if (split == 0 && wave == 0) {
        const float* kr = knew + (size_t)(b * NS + lq) * HID + h * HD + g * 8;
        float4 ka = *reinterpret_cast<const float4*>(kr);
        float4 kb2 = *reinterpret_cast<const float4*>(kr + 4);
        float4 kc2 = *reinterpret_cast<const float4*>(kr + 32);
        float4 kd2 = *reinterpret_cast<const float4*>(kr + 36);
        short8 af0 = pack8(ka, kb2);
        short8 af1 = pack8(kc2, kd2);
        f32x4 sv = {0.f, 0.f, 0.f, 0.f};
        sv = MFMA(af0, qf0, sv);
        sv = MFMA(af1, qf1, sv);

        float tmax = fmaxf(fmaxf(sv[0], sv[1]), fmaxf(sv[2], sv[3]));
        tmax = fmaxf(tmax, __shfl_xor(tmax, 16));
        tmax = fmaxf(tmax, __shfl_xor(tmax, 32));
        float mn = fmaxf(m, tmax);
        float alpha = exp2f(m - mn);
        float e0 = exp2f(sv[0] - mn);
        float e1 = exp2f(sv[1] - mn);
        float e2 = exp2f(sv[2] - mn);
        float e3 = exp2f(sv[3] - mn);
        float rsum = e0 + e1 + e2 + e3;
        rsum += __shfl_xor(rsum, 16);
        rsum += __shfl_xor(rsum, 32);
        lsum = lsum * alpha + rsum;
        m = mn;
        o0 *= alpha; o1 *= alpha; o2 *= alpha; o3 *= alpha;

        short8 pfT;
        pfT[0] = f2bf(e0); pfT[1] = f2bf(e1); pfT[2] = f2bf(e2); pfT[3] = f2bf(e3);
        pfT[4] = 0; pfT[5] = 0; pfT[6] = 0; pfT[7] = 0;

        const float* vt2 = vnew + (size_t)(b * NS) * HID + h * HD;
        #define LOADVT(dst, dcol) do { \
            dst[0] = f2bf(vt2[(size_t)((g << 2) + 0) * HID + (dcol)]); \
            dst[1] = f2bf(vt2[(size_t)((g << 2) + 1) * HID + (dcol)]); \
            dst[2] = f2bf(vt2[(size_t)((g << 2) + 2) * HID + (dcol)]); \
            dst[3] = f2bf(vt2[(size_t)((g << 2) + 3) * HID + (dcol)]); \
            dst[4] = 0; dst[5] = 0; dst[6] = 0; dst[7] = 0; \
        } while (0)
        short8 vv0, vv1, vv2, vv3;
        LOADVT(vv0, lq); LOADVT(vv1, 16 + lq); LOADVT(vv2, 32 + lq); LOADVT(vv3, 48 + lq);
        #undef LOADVT
        o0 = MFMA(vv0, pfT, o0);
        o1 = MFMA(vv1, pfT, o1);
        o2 = MFMA(vv2, pfT, o2);
        o3 = MFMA(vv3, pfT, o3);
    }

    // ---- merge the 4 wave-partials; reuse lds_v slabs as [16 q][64 d] ----
    float* so_w = &lds_v[wave][0][0];
    #define STO(ov, dt) do { \
        so_w[lq * 64 + (dt) * 16 + (g << 2) + 0] = ov[0]; \
        so_w[lq * 64 + (dt) * 16 + (g << 2) + 1] = ov[1]; \
        so_w[lq * 64 + (dt) * 16 + (g << 2) + 2] = ov[2]; \
        so_w[lq * 64 + (dt) * 16 + (g << 2) + 3] = ov[3]; \
    } while (0)
    STO(o0, 0); STO(o1, 1); STO(o2, 2); STO(o3, 3);
    #undef STO
    if (g == 0) { s_m[wave][lq] = m; s_l[wave][lq] = lsum; }
    __syncthreads();

    if (wave == 0) {
        float M = fmaxf(fmaxf(s_m[0][lq], s_m[1][lq]), fmaxf(s_m[2][lq], s_m[3][lq]));
        float aw0 = exp2f(s_m[0][lq] - M);
        float aw1 = exp2f(s_m[1][lq] - M);
        float aw2 = exp2f(s_m[2][lq] - M);
        float aw3 = exp2f(s_m[3][lq] - M);
        float L = aw0 * s_l[0][lq] + aw1 * s_l[1][lq] + aw2 * s_l[2][lq] + aw3 * s_l[3][lq];
        const float* so0 = &lds_v[0][0][0];
        const float* so1 = &lds_v[1][0][0];
        const float* so2 = &lds_v[2][0][0];
        const float* so3 = &lds_v[3][0][0];
        float* pbase = parts + (size_t)bid * PART_STRIDE;
        if (g == 0) { pbase[lq] = M; pbase[16 + lq] = L; }
        for (int dd = 0; dd < 16; ++dd) {
            int di = g * 16 + dd;
            float v = aw0 * so0[lq * 64 + di] + aw1 * so1[lq * 64 + di] +
                      aw2 * so2[lq * 64 + di] + aw3 * so3[lq * 64 + di];
            pbase[32 + lq * 64 + di] = v;
        }
    }
}

// ---------------- merge the 4 split-partials per (b,h) -------------------
__global__ __launch_bounds__(256) void merge_kernel(const float* __restrict__ parts,
                                                    short* __restrict__ attnb) {
    int bh = blockIdx.x;            // b*32 + h
    int tid = threadIdx.x;
    int qi = tid >> 4, ds = (tid & 15) * 4;
    const float* p0 = parts + (size_t)(bh * NSPLIT) * PART_STRIDE;
    const float* p1 = p0 + PART_STRIDE;
    const float* p2 = p1 + PART_STRIDE;
    const float* p3 = p2 + PART_STRIDE;
    float m0 = p0[qi], m1 = p1[qi], m2 = p2[qi], m3 = p3[qi];
    float M = fmaxf(fmaxf(m0, m1), fmaxf(m2, m3));
    float a0 = exp2f(m0 - M), a1 = exp2f(m1 - M), a2 = exp2f(m2 - M), a3 = exp2f(m3 - M);
    float inv = 1.0f / (a0 * p0[16 + qi] + a1 * p1[16 + qi] +
                        a2 * p2[16 + qi] + a3 * p3[16 + qi]);
    int b = bh >> 5, h = bh & 31;
    int base = 32 + qi * 64 + ds;
    float v0 = (a0 * p0[base + 0] + a1 * p1[base + 0] + a2 * p2[base + 0] + a3 * p3[base + 0]) * inv;
    float v1 = (a0 * p0[base + 1] + a1 * p1[base + 1] + a2 * p2[base + 1] + a3 * p3[base + 1]) * inv;
    float v2 = (a0 * p0[base + 2] + a1 * p1[base + 2] + a2 * p2[base + 2] + a3 * p3[base + 2]) * inv;
    float v3 = (a0 * p0[base + 3] + a1 * p1[base + 3] + a2 * p2[base + 3] + a3 * p3[base + 3]) * inv;
    short4v o;
    o[0] = f2bf(v0); o[1] = f2bf(v1); o[2] = f2bf(v2); o[3] = f2bf(v3);
    *reinterpret_cast<short4v*>(attnb + (size_t)(b * NS + qi) * HID + h * HD + ds) = o;
}

extern "C" void kernel_launch(void* const* d_in, const int* in_sizes, int n_in,
                              void* d_out, int out_size, void* d_ws, size_t ws_size,
                              hipStream_t stream) {
    const float* hs     = (const float*)d_in[0];
    const float* past_k = (const float*)d_in[1];
    const float* past_v = (const float*)d_in[2];
    const float* wq     = (const float*)d_in[3];
    const float* wk     = (const float*)d_in[4];
    const float* wv     = (const float*)d_in[5];
    const float* wo     = (const float*)d_in[6];
    float* out = (float*)d_out;

    float* qb    = (float*)d_ws;                  // 128x2048 f32
    float* kn    = qb + MATSZ;                    // 128x2048 f32
    float* vn    = kn + MATSZ;                    // 128x2048 f32
    short* hsb   = (short*)(vn + MATSZ);          // 128x2048 bf16
    short* attnb = hsb + MATSZ;                   // 128x2048 bf16
    float* parts = (float*)(attnb + MATSZ);       // 1024 * PART_STRIDE f32
    float* qkvp  = parts + 1024 * PART_STRIDE;    // 3*4*MATSZ f32 partials
    float* op    = qkvp + 3 * 4 * MATSZ;          // 4*MATSZ f32 partials

    cvt_kernel<<<256, 256, 0, stream>>>(hs, hsb);
    proj_kernel<<<1536, 128, 0, stream>>>(hsb, wq, wk, wv, qkvp);
    merge4_kernel<<<768, 256, 0, stream>>>(qkvp, qb, kn, vn);
    attn_kernel<<<256 * NSPLIT, 256, 0, stream>>>(qb, kn, vn, past_k, past_v, parts);
    merge_kernel<<<256, 256, 0, stream>>>(parts, attnb);
    proj_kernel<<<512, 128, 0, stream>>>(attnb, wo, wo, wo, op);
    merge4_kernel<<<256, 256, 0, stream>>>(op, out, out, out);
}